// Round 1
// baseline (343.681 us; speedup 1.0000x reference)
//
#include <hip/hip_runtime.h>
#include <cstdint>
#include <cstddef>

#define BATCH 8
#define FHh   32
#define FWw   256
#define NA    6
#define NANCH (FHh * FWw * NA)   // 49152
#define PRE_K 2000
#define POST_K 300

// ---------------- workspace layout (bytes) ----------------
// scores   : BATCH*NANCH floats           = 1,572,864
// pre_boxes: BATCH*PRE_K float4 (16B)     =   256,000
// pre_sc   : BATCH*PRE_K floats           =    64,000
// supp     : BATCH*PRE_K*32 u64           = 4,096,000
#define WS_SC_OFF   0
#define WS_PB_OFF   (BATCH * NANCH * 4)                  // 1572864 (16B aligned)
#define WS_PS_OFF   (WS_PB_OFF + BATCH * PRE_K * 16)     // 1828864
#define WS_SUPP_OFF (WS_PS_OFF + BATCH * PRE_K * 4)      // 1892864 (8B aligned)

// ---------------- kernel 1: softmax over A=6 ----------------
__global__ void k_softmax(const float* __restrict__ labels, float* __restrict__ scores) {
    int pos = blockIdx.x * blockDim.x + threadIdx.x;  // over BATCH*FH*FW
    if (pos >= BATCH * FHh * FWw) return;
    const float* in = labels + (size_t)pos * NA;
    float v[NA];
    float m = in[0];
#pragma unroll
    for (int a = 0; a < NA; ++a) { v[a] = in[a]; m = fmaxf(m, v[a]); }
    float s = 0.0f;
#pragma unroll
    for (int a = 0; a < NA; ++a) { v[a] = expf(v[a] - m); s += v[a]; }
    float* o = scores + (size_t)pos * NA;
#pragma unroll
    for (int a = 0; a < NA; ++a) o[a] = v[a] / s;
}

// ------- kernel 2: per-batch exact top-2000 (radix select on distinct u64
//          key), bitonic sort, and box decode. One 1024-thread block/batch. ---
__global__ __launch_bounds__(1024) void k_select(
        const float* __restrict__ scores, const float* __restrict__ deltas,
        const float* __restrict__ anchors,
        float4* __restrict__ pre_boxes, float* __restrict__ pre_scores) {
    const int b = blockIdx.x;
    const int tid = threadIdx.x;
    const float* sc = scores + (size_t)b * NANCH;

    __shared__ unsigned int hist[256];
    __shared__ unsigned long long sh_prefix;
    __shared__ unsigned int sh_r, sh_cnt;
    __shared__ unsigned long long skey[2048];

    if (tid == 0) { sh_prefix = 0ull; sh_r = PRE_K; sh_cnt = 0u; }

    // ---- 8-pass byte radix select: find the exact 2000th-largest key ----
    for (int p = 7; p >= 0; --p) {
        for (int t = tid; t < 256; t += 1024) hist[t] = 0u;
        __syncthreads();
        const unsigned long long prefix = sh_prefix;
        const unsigned long long mask =
            (p == 7) ? 0ull : ((~0ull) << ((p + 1) * 8));
        for (int i = tid; i < NANCH; i += 1024) {
            unsigned long long key =
                ((unsigned long long)__float_as_uint(sc[i]) << 32) |
                (unsigned int)(~i);
            if (((key ^ prefix) & mask) == 0ull) {
                atomicAdd(&hist[(unsigned int)(key >> (p * 8)) & 0xFFu], 1u);
            }
        }
        __syncthreads();
        if (tid == 0) {
            unsigned int r = sh_r, cum = 0u; int sel = 0;
            for (int byte = 255; byte >= 0; --byte) {
                unsigned int h = hist[byte];
                if (cum + h >= r) { sel = byte; sh_r = r - cum; break; }
                cum += h;
            }
            sh_prefix = prefix | ((unsigned long long)sel << (p * 8));
        }
        __syncthreads();
    }
    const unsigned long long cutoff = sh_prefix;  // exact 2000th-largest key

    // ---- gather the exactly-2000 keys >= cutoff (keys are distinct) ----
    for (int t = tid; t < 2048; t += 1024) skey[t] = 0ull;  // pads sort low
    __syncthreads();
    for (int i = tid; i < NANCH; i += 1024) {
        unsigned long long key =
            ((unsigned long long)__float_as_uint(sc[i]) << 32) |
            (unsigned int)(~i);
        if (key >= cutoff) {
            unsigned int pos = atomicAdd(&sh_cnt, 1u);
            if (pos < 2048u) skey[pos] = key;
        }
    }
    __syncthreads();

    // ---- bitonic sort 2048 keys descending ----
    for (int k = 2; k <= 2048; k <<= 1) {
        for (int j = k >> 1; j > 0; j >>= 1) {
            for (int i = tid; i < 2048; i += 1024) {
                int partner = i ^ j;
                if (partner > i) {
                    unsigned long long a = skey[i], c = skey[partner];
                    bool up = ((i & k) == 0);           // descending block
                    if ((a < c) == up) { skey[i] = c; skey[partner] = a; }
                }
            }
            __syncthreads();
        }
    }

    // ---- decode the selected 2000 boxes (same op order as reference) ----
    for (int t = tid; t < PRE_K; t += 1024) {
        unsigned long long key = skey[t];
        int idx = (int)(~(unsigned int)key);
        float score = __uint_as_float((unsigned int)(key >> 32));
        const float* anc = anchors + (size_t)idx * 4;
        const float* del = deltas + ((size_t)b * NANCH + idx) * 4;
        float a0 = anc[0], a1 = anc[1], a2 = anc[2], a3 = anc[3];
        float ah = a2 - a0, aw = a3 - a1;
        float acy = a0 + 0.5f * ah, acx = a1 + 0.5f * aw;
        float d0 = del[0] * 0.1f, d1 = del[1] * 0.1f;
        float d2 = del[2] * 0.2f, d3 = del[3] * 0.2f;
        float bh = expf(d2) * ah, bw = expf(d3) * aw;
        float bcy = d0 * ah + acy, bcx = d1 * aw + acx;
        float y1 = bcy - 0.5f * bh, x1 = bcx - 0.5f * bw;
        pre_boxes[(size_t)b * PRE_K + t] = make_float4(y1, x1, y1 + bh, x1 + bw);
        pre_scores[(size_t)b * PRE_K + t] = score;
    }
}

// ------- kernel 3: suppression bit-matrix. thread = (b, row i, 64-col word w) -
__global__ void k_iou(const float4* __restrict__ pre_boxes,
                      unsigned long long* __restrict__ supp) {
    int gid = blockIdx.x * blockDim.x + threadIdx.x;
    if (gid >= BATCH * PRE_K * 32) return;
    int w = gid & 31;
    int i = (gid >> 5) % PRE_K;
    int b = (gid >> 5) / PRE_K;
    if (w * 64 + 63 <= i) { supp[gid] = 0ull; return; }  // all j <= i
    const float4* boxes = pre_boxes + (size_t)b * PRE_K;
    float4 bi = boxes[i];
    float area_i = (bi.z - bi.x) * (bi.w - bi.y);
    unsigned long long bits = 0ull;
    int j0 = w * 64;
#pragma unroll 4
    for (int t = 0; t < 64; ++t) {
        int j = j0 + t;
        if (j >= PRE_K) break;
        if (j <= i) continue;
        float4 bj = boxes[j];
        float iy1 = fmaxf(bi.x, bj.x), ix1 = fmaxf(bi.y, bj.y);
        float iy2 = fminf(bi.z, bj.z), ix2 = fminf(bi.w, bj.w);
        float inter = fmaxf(iy2 - iy1, 0.0f) * fmaxf(ix2 - ix1, 0.0f);
        float area_j = (bj.z - bj.x) * (bj.w - bj.y);
        float uni = area_i + area_j - inter;
        float iou = inter / fmaxf(uni, 1e-8f);
        if (iou > 0.7f) bits |= (1ull << t);
    }
    supp[gid] = bits;
}

// ------- kernel 4: serial greedy reduce + compact + write outputs.
//          one wave (64 threads) per batch; lanes 0..31 own one u64 word each. -
#define CHNK 16
__global__ void k_final(const unsigned long long* __restrict__ supp,
                        const float4* __restrict__ pre_boxes,
                        const float* __restrict__ pre_scores,
                        float* __restrict__ out) {
    const int b = blockIdx.x;
    const int lane = threadIdx.x;
    float* ob = out + (size_t)b * POST_K * 4;
    float* os = out + (size_t)BATCH * POST_K * 4 + (size_t)b * POST_K;
    for (int t = lane; t < POST_K * 4; t += 64) ob[t] = 0.0f;
    for (int t = lane; t < POST_K; t += 64) os[t] = 0.0f;

    const unsigned long long* S = supp + (size_t)b * PRE_K * 32;
    const int lw = lane & 31;
    unsigned long long removed = 0ull;
    unsigned long long bufA[CHNK], bufB[CHNK];
#pragma unroll
    for (int c = 0; c < CHNK; ++c) bufA[c] = S[(size_t)c * 32 + lw];
    const int NCH = PRE_K / CHNK;  // 125
    for (int ch = 0; ch < NCH; ++ch) {
        const int base = ch * CHNK;
        if (ch + 1 < NCH) {
#pragma unroll
            for (int c = 0; c < CHNK; ++c)
                bufB[c] = S[(size_t)(base + CHNK + c) * 32 + lw];
        }
#pragma unroll
        for (int c = 0; c < CHNK; ++c) {
            const int i = base + c;
            const int wi = i >> 6;
            const int bi = i & 63;
            int cand = (int)((removed >> bi) & 1ull);
            int bit = __builtin_amdgcn_readlane(cand, wi);  // wi is wave-uniform
            if (bit == 0 && lane < 32) removed |= bufA[c];
        }
#pragma unroll
        for (int c = 0; c < CHNK; ++c) bufA[c] = bufB[c];
    }

    // compact kept rows in order -> first POST_K outputs
    unsigned long long kw = ~removed;
    if (lw == 31) kw &= 0xFFFFull;  // rows 1984..1999 only
    int cnt = (lane < 32) ? __builtin_popcountll(kw) : 0;
    int cum = cnt;
#pragma unroll
    for (int d = 1; d < 64; d <<= 1) {
        int v = __shfl_up(cum, d);
        if (lane >= d) cum += v;
    }
    int r = cum - cnt;  // exclusive prefix = output rank of first kept in word
    __syncthreads();    // order zero-fill stores before scatter stores
    if (lane < 32) {
        unsigned long long m = kw;
        while (m != 0ull && r < POST_K) {
            int t = __builtin_ctzll(m);
            m &= m - 1ull;
            int i = lw * 64 + t;
            float4 bx = pre_boxes[(size_t)b * PRE_K + i];
            ob[r * 4 + 0] = fminf(fmaxf(bx.x, 0.0f), 1.0f);
            ob[r * 4 + 1] = fminf(fmaxf(bx.y, 0.0f), 1.0f);
            ob[r * 4 + 2] = fminf(fmaxf(bx.z, 0.0f), 1.0f);
            ob[r * 4 + 3] = fminf(fmaxf(bx.w, 0.0f), 1.0f);
            os[r] = pre_scores[(size_t)b * PRE_K + i];
            ++r;
        }
    }
}

extern "C" void kernel_launch(void* const* d_in, const int* in_sizes, int n_in,
                              void* d_out, int out_size, void* d_ws, size_t ws_size,
                              hipStream_t stream) {
    const float* deltas  = (const float*)d_in[0];  // (8,32,256,24)
    const float* labels  = (const float*)d_in[1];  // (8,32,256,6)
    const float* anchors = (const float*)d_in[2];  // (49152,4)
    float* out = (float*)d_out;                    // 9600 box floats + 2400 scores

    char* ws = (char*)d_ws;
    float* scores          = (float*)(ws + WS_SC_OFF);
    float4* pre_boxes      = (float4*)(ws + WS_PB_OFF);
    float* pre_scores      = (float*)(ws + WS_PS_OFF);
    unsigned long long* sp = (unsigned long long*)(ws + WS_SUPP_OFF);

    k_softmax<<<(BATCH * FHh * FWw + 255) / 256, 256, 0, stream>>>(labels, scores);
    k_select<<<BATCH, 1024, 0, stream>>>(scores, deltas, anchors, pre_boxes, pre_scores);
    k_iou<<<(BATCH * PRE_K * 32 + 255) / 256, 256, 0, stream>>>(pre_boxes, sp);
    k_final<<<BATCH, 64, 0, stream>>>(sp, pre_boxes, pre_scores, out);
}